// Round 9
// baseline (127.021 us; speedup 1.0000x reference)
//
#include <hip/hip_runtime.h>

// GeniePathLayer: GATConv(heads=1,self-loops) -> tanh -> 1-step LSTM
// N=10000, E=320000, D=256. f32 I/O, bf16 MFMA internally.
// 4 launches: k_front (all input-only work) -> k_gx (GEMM | edges | Wcat)
// -> k_gather -> k_lstm.

#define DIM 256
#define MPAD 10112  // 79 * 128
#define CAP 96      // CSR row capacity; in-deg ~Poisson(32), P(>=96) negligible

typedef __attribute__((ext_vector_type(8))) short bf16x8;
typedef __attribute__((ext_vector_type(4))) short s16x4;
typedef __attribute__((ext_vector_type(4))) float f32x4;
typedef __attribute__((ext_vector_type(4))) int i32x4;

typedef const __attribute__((address_space(1))) unsigned gu32;
typedef __attribute__((address_space(3))) unsigned lu32;

__device__ inline unsigned short f2bf(float f){
  unsigned u = __builtin_bit_cast(unsigned, f);
  unsigned r = u + 0x7FFFu + ((u >> 16) & 1u);
  return (unsigned short)(r >> 16);
}
__device__ inline float bf2f(unsigned short s){
  unsigned u = ((unsigned)s) << 16;
  return __builtin_bit_cast(float, u);
}

// All work that depends only on kernel inputs, one launch:
//  blocks [0,80): per-block redundant w_s/w_d = W_gat@att_{s,d} (LDS), then
//                 a_s[n]=x[n].w_s, a_d[n]=x[n].w_d for 125 rows each.
//  blocks [80,1104): grid-stride conv: x->x_bf (+pad), h->A2 right (+pad),
//                 A2 left pad zero, curs zero.
//  blocks [1104,1136): WgT[d][k] = bf16(W_gat[k][d]).
__global__ __launch_bounds__(256) void k_front(
    const float* __restrict__ x, const float* __restrict__ h,
    const float* __restrict__ W_gat, const float* __restrict__ att_s,
    const float* __restrict__ att_d,
    short* __restrict__ x_bf, short* __restrict__ A2, short* __restrict__ WgT,
    float* __restrict__ a_s, float* __restrict__ a_d,
    int* __restrict__ curs, int N){
  int b = blockIdx.x, tid = threadIdx.x;
  int wv = tid >> 6, lane = tid & 63;
  if (b < 80){
    __shared__ float ws[256];
    __shared__ float wd[256];
    f32x4 as4 = ((const f32x4*)att_s)[lane];
    f32x4 ad4 = ((const f32x4*)att_d)[lane];
    for (int j = wv; j < 256; j += 4){
      f32x4 wr = *(const f32x4*)(W_gat + (long)j * 256 + lane * 4);
      float ps = wr[0]*as4[0] + wr[1]*as4[1] + wr[2]*as4[2] + wr[3]*as4[3];
      float pd = wr[0]*ad4[0] + wr[1]*ad4[1] + wr[2]*ad4[2] + wr[3]*ad4[3];
      #pragma unroll
      for (int off = 32; off > 0; off >>= 1){
        ps += __shfl_xor(ps, off);
        pd += __shfl_xor(pd, off);
      }
      if (lane == 0){ ws[j] = ps; wd[j] = pd; }
    }
    __syncthreads();
    f32x4 ws4 = ((const f32x4*)ws)[lane];
    f32x4 wd4 = ((const f32x4*)wd)[lane];
    for (int rr = wv; rr < 125; rr += 4){
      int n = b * 125 + rr;
      if (n >= N) continue;
      f32x4 xv = *(const f32x4*)(x + (long)n * 256 + lane * 4);
      float ps = xv[0]*ws4[0] + xv[1]*ws4[1] + xv[2]*ws4[2] + xv[3]*ws4[3];
      float pd = xv[0]*wd4[0] + xv[1]*wd4[1] + xv[2]*wd4[2] + xv[3]*wd4[3];
      #pragma unroll
      for (int off = 32; off > 0; off >>= 1){
        ps += __shfl_xor(ps, off);
        pd += __shfl_xor(pd, off);
      }
      if (lane == 0){ a_s[n] = ps; a_d[n] = pd; }
    }
  } else if (b < 80 + 1024){
    long zx = (long)MPAD * 64;        // x -> x_bf units (s16x4), incl pad
    long zh = (long)MPAD * 64;        // h -> A2 right half, incl pad
    long zl = (long)(MPAD - N) * 64;  // A2 left half pad rows
    long zc = N / 4;                  // curs zero (i32x4)
    long total = zx + zh + zl + zc;
    long nx64 = (long)N * 64;
    for (long i = (b - 80) * 256L + tid; i < total; i += 1024 * 256L){
      long p = i;
      if (p < zx){
        s16x4 o = {};
        if (p < nx64){
          f32x4 v = ((const f32x4*)x)[p];
          #pragma unroll
          for (int j = 0; j < 4; j++) o[j] = (short)f2bf(v[j]);
        }
        ((s16x4*)x_bf)[p] = o;
        continue;
      }
      p -= zx;
      if (p < zh){
        int n = (int)(p >> 6), c4 = (int)(p & 63);
        s16x4 o = {};
        if (n < N){
          f32x4 v = ((const f32x4*)h)[p];
          #pragma unroll
          for (int j = 0; j < 4; j++) o[j] = (short)f2bf(v[j]);
        }
        *(s16x4*)(A2 + (long)n * 512 + 256 + c4 * 4) = o;
        continue;
      }
      p -= zh;
      if (p < zl){
        int n = N + (int)(p >> 6), c4 = (int)(p & 63);
        s16x4 z = {};
        *(s16x4*)(A2 + (long)n * 512 + c4 * 4) = z;
        continue;
      }
      p -= zl;
      ((i32x4*)curs)[p] = (i32x4){};
    }
  } else {
    for (int p = (b - 80 - 1024) * 256 + tid; p < 16384; p += 32 * 256){
      long i0 = (long)p * 4;
      int d = (int)(i0 >> 8), k = (int)(i0 & 255);
      s16x4 o;
      #pragma unroll
      for (int j = 0; j < 4; j++) o[j] = (short)f2bf(W_gat[(k + j) * 256 + d]);
      *(s16x4*)(WgT + i0) = o;
    }
  }
}

// Fused independent grid: blocks [0,316) = xw_bf GEMM tiles (m97-style);
// [316,316+nchunks) = per-edge softmax scatter into fixed-CAP CSR;
// [316+nchunks, +512) = Wcat bf16 conversion (needed only by k_lstm).
__global__ __launch_bounds__(256) void k_gx(
    const short* __restrict__ xbf, const short* __restrict__ wT,
    const int* __restrict__ ei, const float* __restrict__ a_s,
    const float* __restrict__ a_d,
    const float* __restrict__ W_ih, const float* __restrict__ W_hh,
    short* __restrict__ xw_bf, short* __restrict__ Wcat, int* curs,
    int* __restrict__ csr_s, float* __restrict__ csr_e,
    int E, int N, int nchunks){
  __shared__ short Al[128 * 64];
  __shared__ short Bl[64 * 64];
  int tid = threadIdx.x;
  if (blockIdx.x < 316){
    int bi = blockIdx.x % 79, bj = blockIdx.x / 79;
    int wv = tid >> 6, lane = tid & 63;
    int r = lane & 15, g = lane >> 4;
    f32x4 acc[2][4] = {};
    for (int kt = 0; kt < 256; kt += 64){
      #pragma unroll
      for (int jj = 0; jj < 4; jj++){
        int chunk = jj * 256 + wv * 64 + lane;
        int row = chunk >> 3, cc = chunk & 7;
        int ccs = cc ^ (row & 7);
        const short* gp = xbf + (long)(bi * 128 + row) * 256 + kt + ccs * 8;
        __builtin_amdgcn_global_load_lds((gu32*)gp, (lu32*)&Al[(jj * 256 + wv * 64) * 8], 16, 0, 0);
      }
      #pragma unroll
      for (int jj = 0; jj < 2; jj++){
        int chunk = jj * 256 + wv * 64 + lane;
        int row = chunk >> 3, cc = chunk & 7;
        int ccs = cc ^ (row & 7);
        const short* gp = wT + (long)(bj * 64 + row) * 256 + kt + ccs * 8;
        __builtin_amdgcn_global_load_lds((gu32*)gp, (lu32*)&Bl[(jj * 256 + wv * 64) * 8], 16, 0, 0);
      }
      __syncthreads();
      #pragma unroll
      for (int kk = 0; kk < 2; kk++){
        int kx = kk * 64 + g * 16;
        int sw = kx ^ ((r & 7) << 4);
        bf16x8 a0 = *(const bf16x8*)((const char*)Al + (wv * 32 + r) * 128 + sw);
        bf16x8 a1 = *(const bf16x8*)((const char*)Al + (wv * 32 + 16 + r) * 128 + sw);
        #pragma unroll
        for (int t = 0; t < 4; t++){
          bf16x8 bfr = *(const bf16x8*)((const char*)Bl + (t * 16 + r) * 128 + sw);
          acc[0][t] = __builtin_amdgcn_mfma_f32_16x16x32_bf16(a0, bfr, acc[0][t], 0, 0, 0);
          acc[1][t] = __builtin_amdgcn_mfma_f32_16x16x32_bf16(a1, bfr, acc[1][t], 0, 0, 0);
        }
      }
      __syncthreads();
    }
    int row0 = bi * 128 + wv * 32;
    #pragma unroll
    for (int m = 0; m < 2; m++){
      #pragma unroll
      for (int q = 0; q < 4; q++){
        int row = row0 + m * 16 + g * 4 + q;
        if (row < N){
          #pragma unroll
          for (int t = 0; t < 4; t++){
            xw_bf[(long)row * 256 + bj * 64 + t * 16 + r] = (short)f2bf(acc[m][t][q]);
          }
        }
      }
    }
  } else if (blockIdx.x < 316 + nchunks){
    int t = (blockIdx.x - 316) * 256 + tid;
    if (t < E + N){
      int s = (t < E) ? ei[t] : (t - E);
      int d = (t < E) ? ei[E + t] : (t - E);
      float al = a_s[s] + a_d[d];
      al = (al > 0.f) ? al : 0.2f * al;
      float e = expf(al);
      int pos = atomicAdd(curs + d, 1);
      if (pos < CAP){
        csr_s[d * CAP + pos] = s;
        csr_e[d * CAP + pos] = e;
      }
    }
  } else {
    int p = (blockIdx.x - 316 - nchunks) * 256 + tid;
    if (p < 131072){
      long i0 = (long)p * 4;
      int jr = (int)(i0 >> 9), k = (int)(i0 & 511);
      f32x4 v = (k < 256) ? *(const f32x4*)(W_ih + (long)jr * 256 + k)
                          : *(const f32x4*)(W_hh + (long)jr * 256 + (k - 256));
      s16x4 o;
      #pragma unroll
      for (int j = 0; j < 4; j++) o[j] = (short)f2bf(v[j]);
      *(s16x4*)(Wcat + i0) = o;
    }
  }
}

// per dst row: softmax-weighted gather of bf16 xw rows; denom in-loop;
// xb = tanh(acc/esum + b_gat) -> bf16 into A2 left half. 8-way ILP.
__global__ __launch_bounds__(256) void k_gather(
    const int* __restrict__ curs, const int* __restrict__ csr_s,
    const float* __restrict__ csr_e, const short* __restrict__ xwb,
    const float* __restrict__ b_gat, short* __restrict__ A2, int N){
  int d = blockIdx.x * 4 + (threadIdx.x >> 6);
  if (d >= N) return;
  int lane = threadIdx.x & 63;
  int cnt = curs[d];
  if (cnt > CAP) cnt = CAP;
  int s0 = d * CAP, s1 = s0 + cnt;
  float esum = 0.f;
  float a0 = 0.f, a1 = 0.f, a2 = 0.f, a3 = 0.f;
  int k = s0;
  for (; k + 7 < s1; k += 8){
    int ss[8]; float ee[8]; s16x4 vvv[8];
    #pragma unroll
    for (int u = 0; u < 8; u++){ ss[u] = csr_s[k + u]; ee[u] = csr_e[k + u]; }
    #pragma unroll
    for (int u = 0; u < 8; u++)
      vvv[u] = *(const s16x4*)(xwb + (long)ss[u] * 256 + lane * 4);
    #pragma unroll
    for (int u = 0; u < 8; u++){
      esum += ee[u];
      a0 += ee[u] * bf2f((unsigned short)vvv[u][0]);
      a1 += ee[u] * bf2f((unsigned short)vvv[u][1]);
      a2 += ee[u] * bf2f((unsigned short)vvv[u][2]);
      a3 += ee[u] * bf2f((unsigned short)vvv[u][3]);
    }
  }
  for (; k < s1; k++){
    int s = csr_s[k];
    float e = csr_e[k];
    s16x4 v = *(const s16x4*)(xwb + (long)s * 256 + lane * 4);
    esum += e;
    a0 += e * bf2f((unsigned short)v[0]);
    a1 += e * bf2f((unsigned short)v[1]);
    a2 += e * bf2f((unsigned short)v[2]);
    a3 += e * bf2f((unsigned short)v[3]);
  }
  float inv = 1.0f / esum;
  f32x4 bg = ((const f32x4*)b_gat)[lane];
  s16x4 o;
  o[0] = (short)f2bf(tanhf(a0 * inv + bg[0]));
  o[1] = (short)f2bf(tanhf(a1 * inv + bg[1]));
  o[2] = (short)f2bf(tanhf(a2 * inv + bg[2]));
  o[3] = (short)f2bf(tanhf(a3 * inv + bg[3]));
  *(s16x4*)(A2 + (long)d * 512 + lane * 4) = o;
}

// gates = [xb|h] @ Wcat^T with LDS staging + fused LSTM epilogue.
// Grid (79, 8); block col j covers gate-relative cols [j*32, j*32+32) of all
// 4 gates (B tile rows gate-interleaved) so the epilogue is thread-local.
__global__ __launch_bounds__(256) void k_lstm(
    const short* __restrict__ A2, const short* __restrict__ Wcat,
    const float* __restrict__ c0, float* __restrict__ out, int N){
  __shared__ short Al[128 * 64];
  __shared__ short Bl[128 * 64];
  int w = threadIdx.x >> 6, lane = threadIdx.x & 63;
  int bi = blockIdx.x, j = blockIdx.y;
  int r = lane & 15, g = lane >> 4;
  f32x4 acc[2][8] = {};
  for (int kt = 0; kt < 512; kt += 64){
    #pragma unroll
    for (int jj = 0; jj < 4; jj++){
      int chunk = jj * 256 + w * 64 + lane;
      int row = chunk >> 3, cc = chunk & 7;
      int ccs = cc ^ (row & 7);
      const short* gpa = A2 + (long)(bi * 128 + row) * 512 + kt + ccs * 8;
      __builtin_amdgcn_global_load_lds((gu32*)gpa, (lu32*)&Al[(jj * 256 + w * 64) * 8], 16, 0, 0);
      int brow = (row >> 5) * 256 + j * 32 + (row & 31);
      const short* gpb = Wcat + (long)brow * 512 + kt + ccs * 8;
      __builtin_amdgcn_global_load_lds((gu32*)gpb, (lu32*)&Bl[(jj * 256 + w * 64) * 8], 16, 0, 0);
    }
    __syncthreads();
    #pragma unroll
    for (int kk = 0; kk < 2; kk++){
      int kx = kk * 64 + g * 16;
      int sw = kx ^ ((r & 7) << 4);
      bf16x8 a0 = *(const bf16x8*)((const char*)Al + (w * 32 + r) * 128 + sw);
      bf16x8 a1 = *(const bf16x8*)((const char*)Al + (w * 32 + 16 + r) * 128 + sw);
      #pragma unroll
      for (int t = 0; t < 8; t++){
        bf16x8 b = *(const bf16x8*)((const char*)Bl + (t * 16 + r) * 128 + sw);
        acc[0][t] = __builtin_amdgcn_mfma_f32_16x16x32_bf16(a0, b, acc[0][t], 0, 0, 0);
        acc[1][t] = __builtin_amdgcn_mfma_f32_16x16x32_bf16(a1, b, acc[1][t], 0, 0, 0);
      }
    }
    __syncthreads();
  }
  long sec = (long)N * 256;
  int row0 = bi * 128 + w * 32;
  #pragma unroll
  for (int m = 0; m < 2; m++){
    #pragma unroll
    for (int q = 0; q < 4; q++){
      int row = row0 + m * 16 + g * 4 + q;
      if (row >= N) continue;
      #pragma unroll
      for (int dc = 0; dc < 2; dc++){
        int dcol = j * 32 + dc * 16 + r;
        float iv = acc[m][dc][q];
        float fv = acc[m][dc + 2][q];
        float gv = acc[m][dc + 4][q];
        float ov = acc[m][dc + 6][q];
        long idx = (long)row * 256 + dcol;
        float c0v = c0[idx];
        float ii = 1.f / (1.f + expf(-iv));
        float ff = 1.f / (1.f + expf(-fv));
        float gg = tanhf(gv);
        float oo = 1.f / (1.f + expf(-ov));
        float c1 = ff * c0v + ii * gg;
        float h1 = oo * tanhf(c1);
        out[idx] = h1;
        out[sec + idx] = h1;
        out[2 * sec + idx] = c1;
      }
    }
  }
}

extern "C" void kernel_launch(void* const* d_in, const int* in_sizes, int n_in,
                              void* d_out, int out_size, void* d_ws, size_t ws_size,
                              hipStream_t stream){
  const float* x     = (const float*)d_in[0];
  const int*   ei    = (const int*)d_in[1];
  const float* h     = (const float*)d_in[2];
  const float* c     = (const float*)d_in[3];
  const float* W_gat = (const float*)d_in[4];
  const float* att_s = (const float*)d_in[5];
  const float* att_d = (const float*)d_in[6];
  const float* b_gat = (const float*)d_in[7];
  const float* W_ih  = (const float*)d_in[8];
  const float* W_hh  = (const float*)d_in[9];
  int N  = in_sizes[0] / DIM;   // 10000
  int E  = in_sizes[1] / 2;     // 320000

  char* ws = (char*)d_ws;
  size_t off = 0;
  auto alloc = [&](size_t bytes) -> void* {
    void* p = ws + off;
    off += (bytes + 255) & ~(size_t)255;
    return p;
  };
  short* xw_bf = (short*)alloc((size_t)MPAD * 256 * 2);
  short* A2    = (short*)alloc((size_t)MPAD * 512 * 2);
  short* x_bf  = (short*)alloc((size_t)MPAD * 256 * 2);
  short* Wcat  = (short*)alloc((size_t)1024 * 512 * 2);
  short* WgT   = (short*)alloc((size_t)256 * 256 * 2);
  float* a_s   = (float*)alloc((size_t)N * 4);
  float* a_d   = (float*)alloc((size_t)N * 4);
  int*   curs  = (int*)alloc((size_t)N * 4);
  int*   csr_s = (int*)alloc((size_t)N * CAP * 4);
  float* csr_e = (float*)alloc((size_t)N * CAP * 4);

  float* out = (float*)d_out;

  int nchunks = (E + N + 255) / 256;  // 1290
  hipLaunchKernelGGL(k_front, dim3(80 + 1024 + 32), dim3(256), 0, stream,
                     x, h, W_gat, att_s, att_d,
                     x_bf, A2, WgT, a_s, a_d, curs, N);
  hipLaunchKernelGGL(k_gx, dim3(316 + nchunks + 512), dim3(256), 0, stream,
                     x_bf, WgT, ei, a_s, a_d, W_ih, W_hh,
                     xw_bf, Wcat, curs, csr_s, csr_e, E, N, nchunks);
  hipLaunchKernelGGL(k_gather, dim3(N / 4), dim3(256), 0, stream,
                     curs, csr_s, csr_e, xw_bf, b_gat, A2, N);
  hipLaunchKernelGGL(k_lstm, dim3(MPAD / 128, 8), dim3(256), 0, stream,
                     A2, Wcat, c, out, N);
}

// Round 10
// 92.774 us; speedup vs baseline: 1.3691x; 1.3691x over previous
//
#include <hip/hip_runtime.h>

// GeniePathLayer: GATConv(heads=1,self-loops) -> tanh -> 1-step LSTM
// N=10000, E=320000, D=256. f32 I/O, bf16 MFMA internally.
// 4 launches:
//  k_front  (input-only: conversions, WgT, Wcat, w_s/w_d, zero curs)
//  k_gx     (GEMM tiles | a_s/a_d row dots | src-only CSR scatter)
//  k_gather (on-the-fly e = exp(leaky(a_s[s]+a_d[d])), weighted gather)
//  k_lstm   (gates GEMM + fused epilogue)

#define DIM 256
#define MPAD 10112  // 79 * 128
#define CAP 96      // CSR row capacity; in-deg ~Poisson(32), P(>=96) negligible

typedef __attribute__((ext_vector_type(8))) short bf16x8;
typedef __attribute__((ext_vector_type(4))) short s16x4;
typedef __attribute__((ext_vector_type(4))) float f32x4;
typedef __attribute__((ext_vector_type(4))) int i32x4;

typedef const __attribute__((address_space(1))) unsigned gu32;
typedef __attribute__((address_space(3))) unsigned lu32;

__device__ inline unsigned short f2bf(float f){
  unsigned u = __builtin_bit_cast(unsigned, f);
  unsigned r = u + 0x7FFFu + ((u >> 16) & 1u);
  return (unsigned short)(r >> 16);
}
__device__ inline float bf2f(unsigned short s){
  unsigned u = ((unsigned)s) << 16;
  return __builtin_bit_cast(float, u);
}

// All input-only work, one launch:
//  [0,1024)      grid-stride conv: x->x_bf (+pad), h->A2 right (+pad),
//                A2 left pad zero, curs zero.
//  [1024,1056)   WgT[d][k] = bf16(W_gat[k][d]).
//  1056 / 1057   w_s / w_d = W_gat @ att_{s,d}; one 256-dot per thread.
//  [1058,1570)   Wcat[j] = [W_ih[j] | W_hh[j]] bf16.
__global__ __launch_bounds__(256) void k_front(
    const float* __restrict__ x, const float* __restrict__ h,
    const float* __restrict__ W_gat, const float* __restrict__ att_s,
    const float* __restrict__ att_d,
    const float* __restrict__ W_ih, const float* __restrict__ W_hh,
    short* __restrict__ x_bf, short* __restrict__ A2, short* __restrict__ WgT,
    short* __restrict__ Wcat,
    float* __restrict__ w_s, float* __restrict__ w_d,
    int* __restrict__ curs, int N){
  int b = blockIdx.x, tid = threadIdx.x;
  if (b < 1024){
    long zx = (long)MPAD * 64;        // x -> x_bf units (s16x4), incl pad
    long zh = (long)MPAD * 64;        // h -> A2 right half, incl pad
    long zl = (long)(MPAD - N) * 64;  // A2 left half pad rows
    long zc = N / 4;                  // curs zero (i32x4)
    long total = zx + zh + zl + zc;
    long nx64 = (long)N * 64;
    for (long i = b * 256L + tid; i < total; i += 1024 * 256L){
      long p = i;
      if (p < zx){
        s16x4 o = {};
        if (p < nx64){
          f32x4 v = ((const f32x4*)x)[p];
          #pragma unroll
          for (int j = 0; j < 4; j++) o[j] = (short)f2bf(v[j]);
        }
        ((s16x4*)x_bf)[p] = o;
        continue;
      }
      p -= zx;
      if (p < zh){
        int n = (int)(p >> 6), c4 = (int)(p & 63);
        s16x4 o = {};
        if (n < N){
          f32x4 v = ((const f32x4*)h)[p];
          #pragma unroll
          for (int j = 0; j < 4; j++) o[j] = (short)f2bf(v[j]);
        }
        *(s16x4*)(A2 + (long)n * 512 + 256 + c4 * 4) = o;
        continue;
      }
      p -= zh;
      if (p < zl){
        int n = N + (int)(p >> 6), c4 = (int)(p & 63);
        s16x4 z = {};
        *(s16x4*)(A2 + (long)n * 512 + c4 * 4) = z;
        continue;
      }
      p -= zl;
      ((i32x4*)curs)[p] = (i32x4){};
    }
  } else if (b < 1056){
    for (int p = (b - 1024) * 256 + tid; p < 16384; p += 32 * 256){
      long i0 = (long)p * 4;
      int d = (int)(i0 >> 8), k = (int)(i0 & 255);
      s16x4 o;
      #pragma unroll
      for (int j = 0; j < 4; j++) o[j] = (short)f2bf(W_gat[(k + j) * 256 + d]);
      *(s16x4*)(WgT + i0) = o;
    }
  } else if (b < 1058){
    const float* av = (b == 1056) ? att_s : att_d;
    float* wout = (b == 1056) ? w_s : w_d;
    int k = tid;
    const float* row = W_gat + (long)k * 256;
    float acc = 0.f;
    for (int dd = 0; dd < 256; dd += 4){
      f32x4 wv = *(const f32x4*)(row + dd);
      f32x4 a4 = *(const f32x4*)(av + dd);
      acc += wv[0]*a4[0] + wv[1]*a4[1] + wv[2]*a4[2] + wv[3]*a4[3];
    }
    wout[k] = acc;
  } else {
    int p = (b - 1058) * 256 + tid;
    if (p < 131072){
      long i0 = (long)p * 4;
      int jr = (int)(i0 >> 9), k = (int)(i0 & 511);
      f32x4 v = (k < 256) ? *(const f32x4*)(W_ih + (long)jr * 256 + k)
                          : *(const f32x4*)(W_hh + (long)jr * 256 + (k - 256));
      s16x4 o;
      #pragma unroll
      for (int j = 0; j < 4; j++) o[j] = (short)f2bf(v[j]);
      *(s16x4*)(Wcat + i0) = o;
    }
  }
}

// Fused independent grid:
//  [0,316)          xw_bf GEMM tiles (m97-style 128x64 LDS staging).
//  [316,948)        a_s[n]=x_bf[n].w_s, a_d[n]=x_bf[n].w_d (wave per row).
//  [948,948+nchunk) src-only CSR scatter: csr_s[d*CAP + pos] = s.
__global__ __launch_bounds__(256) void k_gx(
    const short* __restrict__ xbf, const short* __restrict__ wT,
    const int* __restrict__ ei,
    const float* __restrict__ w_s, const float* __restrict__ w_d,
    short* __restrict__ xw_bf, float* __restrict__ a_s, float* __restrict__ a_d,
    int* curs, int* __restrict__ csr_s, int E, int N){
  __shared__ short Al[128 * 64];
  __shared__ short Bl[64 * 64];
  int tid = threadIdx.x;
  if (blockIdx.x < 316){
    int bi = blockIdx.x % 79, bj = blockIdx.x / 79;
    int wv = tid >> 6, lane = tid & 63;
    int r = lane & 15, g = lane >> 4;
    f32x4 acc[2][4] = {};
    for (int kt = 0; kt < 256; kt += 64){
      #pragma unroll
      for (int jj = 0; jj < 4; jj++){
        int chunk = jj * 256 + wv * 64 + lane;
        int row = chunk >> 3, cc = chunk & 7;
        int ccs = cc ^ (row & 7);
        const short* gp = xbf + (long)(bi * 128 + row) * 256 + kt + ccs * 8;
        __builtin_amdgcn_global_load_lds((gu32*)gp, (lu32*)&Al[(jj * 256 + wv * 64) * 8], 16, 0, 0);
      }
      #pragma unroll
      for (int jj = 0; jj < 2; jj++){
        int chunk = jj * 256 + wv * 64 + lane;
        int row = chunk >> 3, cc = chunk & 7;
        int ccs = cc ^ (row & 7);
        const short* gp = wT + (long)(bj * 64 + row) * 256 + kt + ccs * 8;
        __builtin_amdgcn_global_load_lds((gu32*)gp, (lu32*)&Bl[(jj * 256 + wv * 64) * 8], 16, 0, 0);
      }
      __syncthreads();
      #pragma unroll
      for (int kk = 0; kk < 2; kk++){
        int kx = kk * 64 + g * 16;
        int sw = kx ^ ((r & 7) << 4);
        bf16x8 a0 = *(const bf16x8*)((const char*)Al + (wv * 32 + r) * 128 + sw);
        bf16x8 a1 = *(const bf16x8*)((const char*)Al + (wv * 32 + 16 + r) * 128 + sw);
        #pragma unroll
        for (int t = 0; t < 4; t++){
          bf16x8 bfr = *(const bf16x8*)((const char*)Bl + (t * 16 + r) * 128 + sw);
          acc[0][t] = __builtin_amdgcn_mfma_f32_16x16x32_bf16(a0, bfr, acc[0][t], 0, 0, 0);
          acc[1][t] = __builtin_amdgcn_mfma_f32_16x16x32_bf16(a1, bfr, acc[1][t], 0, 0, 0);
        }
      }
      __syncthreads();
    }
    int row0 = bi * 128 + wv * 32;
    #pragma unroll
    for (int m = 0; m < 2; m++){
      #pragma unroll
      for (int q = 0; q < 4; q++){
        int row = row0 + m * 16 + g * 4 + q;
        if (row < N){
          #pragma unroll
          for (int t = 0; t < 4; t++){
            xw_bf[(long)row * 256 + bj * 64 + t * 16 + r] = (short)f2bf(acc[m][t][q]);
          }
        }
      }
    }
  } else if (blockIdx.x < 948){
    int wv = tid >> 6, lane = tid & 63;
    f32x4 ws4 = ((const f32x4*)w_s)[lane];
    f32x4 wd4 = ((const f32x4*)w_d)[lane];
    int n0 = (blockIdx.x - 316) * 16 + wv * 4;
    for (int rr = 0; rr < 4; rr++){
      int n = n0 + rr;
      if (n >= N) continue;
      s16x4 xv = *(const s16x4*)(xbf + (long)n * 256 + lane * 4);
      float x0 = bf2f((unsigned short)xv[0]), x1 = bf2f((unsigned short)xv[1]);
      float x2 = bf2f((unsigned short)xv[2]), x3 = bf2f((unsigned short)xv[3]);
      float ps = x0*ws4[0] + x1*ws4[1] + x2*ws4[2] + x3*ws4[3];
      float pd = x0*wd4[0] + x1*wd4[1] + x2*wd4[2] + x3*wd4[3];
      #pragma unroll
      for (int off = 32; off > 0; off >>= 1){
        ps += __shfl_xor(ps, off);
        pd += __shfl_xor(pd, off);
      }
      if (lane == 0){ a_s[n] = ps; a_d[n] = pd; }
    }
  } else {
    int t = (blockIdx.x - 948) * 256 + tid;
    if (t < E + N){
      int s = (t < E) ? ei[t] : (t - E);
      int d = (t < E) ? ei[E + t] : (t - E);
      int pos = atomicAdd(curs + d, 1);
      if (pos < CAP) csr_s[d * CAP + pos] = s;
    }
  }
}

// per dst row: e = exp(leaky(a_s[s]+a_d[d])) computed on the fly; softmax-
// weighted gather of bf16 xw rows (denom in-loop); xb = tanh(acc/esum+b_gat)
// -> bf16 into A2 left half. 8-way ILP.
__global__ __launch_bounds__(256) void k_gather(
    const int* __restrict__ curs, const int* __restrict__ csr_s,
    const float* __restrict__ a_s, const float* __restrict__ a_d,
    const short* __restrict__ xwb, const float* __restrict__ b_gat,
    short* __restrict__ A2, int N){
  int d = blockIdx.x * 4 + (threadIdx.x >> 6);
  if (d >= N) return;
  int lane = threadIdx.x & 63;
  int cnt = curs[d];
  if (cnt > CAP) cnt = CAP;
  int s0 = d * CAP, s1 = s0 + cnt;
  float add = a_d[d];
  float esum = 0.f;
  float a0 = 0.f, a1 = 0.f, a2 = 0.f, a3 = 0.f;
  int k = s0;
  for (; k + 7 < s1; k += 8){
    int ss[8]; float ee[8]; s16x4 vvv[8];
    #pragma unroll
    for (int u = 0; u < 8; u++) ss[u] = csr_s[k + u];
    #pragma unroll
    for (int u = 0; u < 8; u++)
      vvv[u] = *(const s16x4*)(xwb + (long)ss[u] * 256 + lane * 4);
    #pragma unroll
    for (int u = 0; u < 8; u++){
      float al = a_s[ss[u]] + add;
      al = (al > 0.f) ? al : 0.2f * al;
      ee[u] = __expf(al);
    }
    #pragma unroll
    for (int u = 0; u < 8; u++){
      esum += ee[u];
      a0 += ee[u] * bf2f((unsigned short)vvv[u][0]);
      a1 += ee[u] * bf2f((unsigned short)vvv[u][1]);
      a2 += ee[u] * bf2f((unsigned short)vvv[u][2]);
      a3 += ee[u] * bf2f((unsigned short)vvv[u][3]);
    }
  }
  for (; k < s1; k++){
    int s = csr_s[k];
    float al = a_s[s] + add;
    al = (al > 0.f) ? al : 0.2f * al;
    float e = __expf(al);
    s16x4 v = *(const s16x4*)(xwb + (long)s * 256 + lane * 4);
    esum += e;
    a0 += e * bf2f((unsigned short)v[0]);
    a1 += e * bf2f((unsigned short)v[1]);
    a2 += e * bf2f((unsigned short)v[2]);
    a3 += e * bf2f((unsigned short)v[3]);
  }
  float inv = 1.0f / esum;
  f32x4 bg = ((const f32x4*)b_gat)[lane];
  s16x4 o;
  o[0] = (short)f2bf(tanhf(a0 * inv + bg[0]));
  o[1] = (short)f2bf(tanhf(a1 * inv + bg[1]));
  o[2] = (short)f2bf(tanhf(a2 * inv + bg[2]));
  o[3] = (short)f2bf(tanhf(a3 * inv + bg[3]));
  *(s16x4*)(A2 + (long)d * 512 + lane * 4) = o;
}

// gates = [xb|h] @ Wcat^T with LDS staging + fused LSTM epilogue.
// Grid (79, 8); block col j covers gate-relative cols [j*32, j*32+32) of all
// 4 gates (B tile rows gate-interleaved) so the epilogue is thread-local.
__global__ __launch_bounds__(256) void k_lstm(
    const short* __restrict__ A2, const short* __restrict__ Wcat,
    const float* __restrict__ c0, float* __restrict__ out, int N){
  __shared__ short Al[128 * 64];
  __shared__ short Bl[128 * 64];
  int w = threadIdx.x >> 6, lane = threadIdx.x & 63;
  int bi = blockIdx.x, j = blockIdx.y;
  int r = lane & 15, g = lane >> 4;
  f32x4 acc[2][8] = {};
  for (int kt = 0; kt < 512; kt += 64){
    #pragma unroll
    for (int jj = 0; jj < 4; jj++){
      int chunk = jj * 256 + w * 64 + lane;
      int row = chunk >> 3, cc = chunk & 7;
      int ccs = cc ^ (row & 7);
      const short* gpa = A2 + (long)(bi * 128 + row) * 512 + kt + ccs * 8;
      __builtin_amdgcn_global_load_lds((gu32*)gpa, (lu32*)&Al[(jj * 256 + w * 64) * 8], 16, 0, 0);
      int brow = (row >> 5) * 256 + j * 32 + (row & 31);
      const short* gpb = Wcat + (long)brow * 512 + kt + ccs * 8;
      __builtin_amdgcn_global_load_lds((gu32*)gpb, (lu32*)&Bl[(jj * 256 + w * 64) * 8], 16, 0, 0);
    }
    __syncthreads();
    #pragma unroll
    for (int kk = 0; kk < 2; kk++){
      int kx = kk * 64 + g * 16;
      int sw = kx ^ ((r & 7) << 4);
      bf16x8 a0 = *(const bf16x8*)((const char*)Al + (w * 32 + r) * 128 + sw);
      bf16x8 a1 = *(const bf16x8*)((const char*)Al + (w * 32 + 16 + r) * 128 + sw);
      #pragma unroll
      for (int t = 0; t < 8; t++){
        bf16x8 b = *(const bf16x8*)((const char*)Bl + (t * 16 + r) * 128 + sw);
        acc[0][t] = __builtin_amdgcn_mfma_f32_16x16x32_bf16(a0, b, acc[0][t], 0, 0, 0);
        acc[1][t] = __builtin_amdgcn_mfma_f32_16x16x32_bf16(a1, b, acc[1][t], 0, 0, 0);
      }
    }
    __syncthreads();
  }
  long sec = (long)N * 256;
  int row0 = bi * 128 + w * 32;
  #pragma unroll
  for (int m = 0; m < 2; m++){
    #pragma unroll
    for (int q = 0; q < 4; q++){
      int row = row0 + m * 16 + g * 4 + q;
      if (row >= N) continue;
      #pragma unroll
      for (int dc = 0; dc < 2; dc++){
        int dcol = j * 32 + dc * 16 + r;
        float iv = acc[m][dc][q];
        float fv = acc[m][dc + 2][q];
        float gv = acc[m][dc + 4][q];
        float ov = acc[m][dc + 6][q];
        long idx = (long)row * 256 + dcol;
        float c0v = c0[idx];
        float ii = 1.f / (1.f + expf(-iv));
        float ff = 1.f / (1.f + expf(-fv));
        float gg = tanhf(gv);
        float oo = 1.f / (1.f + expf(-ov));
        float c1 = ff * c0v + ii * gg;
        float h1 = oo * tanhf(c1);
        out[idx] = h1;
        out[sec + idx] = h1;
        out[2 * sec + idx] = c1;
      }
    }
  }
}

extern "C" void kernel_launch(void* const* d_in, const int* in_sizes, int n_in,
                              void* d_out, int out_size, void* d_ws, size_t ws_size,
                              hipStream_t stream){
  const float* x     = (const float*)d_in[0];
  const int*   ei    = (const int*)d_in[1];
  const float* h     = (const float*)d_in[2];
  const float* c     = (const float*)d_in[3];
  const float* W_gat = (const float*)d_in[4];
  const float* att_s = (const float*)d_in[5];
  const float* att_d = (const float*)d_in[6];
  const float* b_gat = (const float*)d_in[7];
  const float* W_ih  = (const float*)d_in[8];
  const float* W_hh  = (const float*)d_in[9];
  int N  = in_sizes[0] / DIM;   // 10000
  int E  = in_sizes[1] / 2;     // 320000

  char* ws = (char*)d_ws;
  size_t off = 0;
  auto alloc = [&](size_t bytes) -> void* {
    void* p = ws + off;
    off += (bytes + 255) & ~(size_t)255;
    return p;
  };
  short* xw_bf = (short*)alloc((size_t)MPAD * 256 * 2);
  short* A2    = (short*)alloc((size_t)MPAD * 512 * 2);
  short* x_bf  = (short*)alloc((size_t)MPAD * 256 * 2);
  short* Wcat  = (short*)alloc((size_t)1024 * 512 * 2);
  short* WgT   = (short*)alloc((size_t)256 * 256 * 2);
  float* w_s   = (float*)alloc((size_t)256 * 4);
  float* w_d   = (float*)alloc((size_t)256 * 4);
  float* a_s   = (float*)alloc((size_t)N * 4);
  float* a_d   = (float*)alloc((size_t)N * 4);
  int*   curs  = (int*)alloc((size_t)N * 4);
  int*   csr_s = (int*)alloc((size_t)N * CAP * 4);

  float* out = (float*)d_out;

  int nchunks = (E + N + 255) / 256;  // 1290
  hipLaunchKernelGGL(k_front, dim3(1570), dim3(256), 0, stream,
                     x, h, W_gat, att_s, att_d, W_ih, W_hh,
                     x_bf, A2, WgT, Wcat, w_s, w_d, curs, N);
  hipLaunchKernelGGL(k_gx, dim3(948 + nchunks), dim3(256), 0, stream,
                     x_bf, WgT, ei, w_s, w_d, xw_bf, a_s, a_d,
                     curs, csr_s, E, N);
  hipLaunchKernelGGL(k_gather, dim3(N / 4), dim3(256), 0, stream,
                     curs, csr_s, a_s, a_d, xw_bf, b_gat, A2, N);
  hipLaunchKernelGGL(k_lstm, dim3(MPAD / 128, 8), dim3(256), 0, stream,
                     A2, Wcat, c, out, N);
}

// Round 11
// 86.844 us; speedup vs baseline: 1.4626x; 1.0683x over previous
//
#include <hip/hip_runtime.h>

// GeniePathLayer: GATConv(heads=1,self-loops) -> tanh -> 1-step LSTM
// N=10000, E=320000, D=256. f32 I/O, bf16 MFMA internally, fp8 xw staging.
// 4 launches:
//  k_front  (input-only: conversions, WgT, Wcat, w_s/w_d, zero curs)
//  k_gx     (GEMM tiles -> fp8 xw | a_s/a_d row dots | src-only CSR scatter)
//  k_gather (on-the-fly e = exp(leaky(a_s[s]+a_d[d])), fp8 weighted gather)
//  k_lstm   (gates GEMM + fused epilogue)

#define DIM 256
#define MPAD 10112  // 79 * 128
#define CAP 96      // CSR row capacity; in-deg ~Poisson(32), P(>=96) negligible

typedef __attribute__((ext_vector_type(8))) short bf16x8;
typedef __attribute__((ext_vector_type(4))) short s16x4;
typedef __attribute__((ext_vector_type(4))) float f32x4;
typedef __attribute__((ext_vector_type(2))) float f32x2;
typedef __attribute__((ext_vector_type(4))) int i32x4;

typedef const __attribute__((address_space(1))) unsigned gu32;
typedef __attribute__((address_space(3))) unsigned lu32;

__device__ inline unsigned short f2bf(float f){
  unsigned u = __builtin_bit_cast(unsigned, f);
  unsigned r = u + 0x7FFFu + ((u >> 16) & 1u);
  return (unsigned short)(r >> 16);
}
__device__ inline float bf2f(unsigned short s){
  unsigned u = ((unsigned)s) << 16;
  return __builtin_bit_cast(float, u);
}

// All input-only work, one launch:
//  [0,1024)      grid-stride conv: x->x_bf (+pad), h->A2 right (+pad),
//                A2 left pad zero, curs zero.
//  [1024,1056)   WgT[d][k] = bf16(W_gat[k][d]).
//  1056 / 1057   w_s / w_d = W_gat @ att_{s,d}; one 256-dot per thread.
//  [1058,1570)   Wcat[j] = [W_ih[j] | W_hh[j]] bf16.
__global__ __launch_bounds__(256) void k_front(
    const float* __restrict__ x, const float* __restrict__ h,
    const float* __restrict__ W_gat, const float* __restrict__ att_s,
    const float* __restrict__ att_d,
    const float* __restrict__ W_ih, const float* __restrict__ W_hh,
    short* __restrict__ x_bf, short* __restrict__ A2, short* __restrict__ WgT,
    short* __restrict__ Wcat,
    float* __restrict__ w_s, float* __restrict__ w_d,
    int* __restrict__ curs, int N){
  int b = blockIdx.x, tid = threadIdx.x;
  if (b < 1024){
    long zx = (long)MPAD * 64;        // x -> x_bf units (s16x4), incl pad
    long zh = (long)MPAD * 64;        // h -> A2 right half, incl pad
    long zl = (long)(MPAD - N) * 64;  // A2 left half pad rows
    long zc = N / 4;                  // curs zero (i32x4)
    long total = zx + zh + zl + zc;
    long nx64 = (long)N * 64;
    for (long i = b * 256L + tid; i < total; i += 1024 * 256L){
      long p = i;
      if (p < zx){
        s16x4 o = {};
        if (p < nx64){
          f32x4 v = ((const f32x4*)x)[p];
          #pragma unroll
          for (int j = 0; j < 4; j++) o[j] = (short)f2bf(v[j]);
        }
        ((s16x4*)x_bf)[p] = o;
        continue;
      }
      p -= zx;
      if (p < zh){
        int n = (int)(p >> 6), c4 = (int)(p & 63);
        s16x4 o = {};
        if (n < N){
          f32x4 v = ((const f32x4*)h)[p];
          #pragma unroll
          for (int j = 0; j < 4; j++) o[j] = (short)f2bf(v[j]);
        }
        *(s16x4*)(A2 + (long)n * 512 + 256 + c4 * 4) = o;
        continue;
      }
      p -= zh;
      if (p < zl){
        int n = N + (int)(p >> 6), c4 = (int)(p & 63);
        s16x4 z = {};
        *(s16x4*)(A2 + (long)n * 512 + c4 * 4) = z;
        continue;
      }
      p -= zl;
      ((i32x4*)curs)[p] = (i32x4){};
    }
  } else if (b < 1056){
    for (int p = (b - 1024) * 256 + tid; p < 16384; p += 32 * 256){
      long i0 = (long)p * 4;
      int d = (int)(i0 >> 8), k = (int)(i0 & 255);
      s16x4 o;
      #pragma unroll
      for (int j = 0; j < 4; j++) o[j] = (short)f2bf(W_gat[(k + j) * 256 + d]);
      *(s16x4*)(WgT + i0) = o;
    }
  } else if (b < 1058){
    const float* av = (b == 1056) ? att_s : att_d;
    float* wout = (b == 1056) ? w_s : w_d;
    int k = tid;
    const float* row = W_gat + (long)k * 256;
    float acc = 0.f;
    for (int dd = 0; dd < 256; dd += 4){
      f32x4 wv = *(const f32x4*)(row + dd);
      f32x4 a4 = *(const f32x4*)(av + dd);
      acc += wv[0]*a4[0] + wv[1]*a4[1] + wv[2]*a4[2] + wv[3]*a4[3];
    }
    wout[k] = acc;
  } else {
    int p = (b - 1058) * 256 + tid;
    if (p < 131072){
      long i0 = (long)p * 4;
      int jr = (int)(i0 >> 9), k = (int)(i0 & 511);
      f32x4 v = (k < 256) ? *(const f32x4*)(W_ih + (long)jr * 256 + k)
                          : *(const f32x4*)(W_hh + (long)jr * 256 + (k - 256));
      s16x4 o;
      #pragma unroll
      for (int j = 0; j < 4; j++) o[j] = (short)f2bf(v[j]);
      *(s16x4*)(Wcat + i0) = o;
    }
  }
}

// Fused independent grid:
//  [0,316)          xw GEMM tiles (m97-style), epilogue encodes OCP fp8 e4m3.
//  [316,948)        a_s[n]=x_bf[n].w_s, a_d[n]=x_bf[n].w_d (wave per row).
//  [948,948+nchunk) src-only CSR scatter: csr_s[d*CAP + pos] = s.
__global__ __launch_bounds__(256) void k_gx(
    const short* __restrict__ xbf, const short* __restrict__ wT,
    const int* __restrict__ ei,
    const float* __restrict__ w_s, const float* __restrict__ w_d,
    unsigned char* __restrict__ xw8, float* __restrict__ a_s, float* __restrict__ a_d,
    int* curs, int* __restrict__ csr_s, int E, int N){
  __shared__ short Al[128 * 64];
  __shared__ short Bl[64 * 64];
  int tid = threadIdx.x;
  if (blockIdx.x < 316){
    int bi = blockIdx.x % 79, bj = blockIdx.x / 79;
    int wv = tid >> 6, lane = tid & 63;
    int r = lane & 15, g = lane >> 4;
    f32x4 acc[2][4] = {};
    for (int kt = 0; kt < 256; kt += 64){
      #pragma unroll
      for (int jj = 0; jj < 4; jj++){
        int chunk = jj * 256 + wv * 64 + lane;
        int row = chunk >> 3, cc = chunk & 7;
        int ccs = cc ^ (row & 7);
        const short* gp = xbf + (long)(bi * 128 + row) * 256 + kt + ccs * 8;
        __builtin_amdgcn_global_load_lds((gu32*)gp, (lu32*)&Al[(jj * 256 + wv * 64) * 8], 16, 0, 0);
      }
      #pragma unroll
      for (int jj = 0; jj < 2; jj++){
        int chunk = jj * 256 + wv * 64 + lane;
        int row = chunk >> 3, cc = chunk & 7;
        int ccs = cc ^ (row & 7);
        const short* gp = wT + (long)(bj * 64 + row) * 256 + kt + ccs * 8;
        __builtin_amdgcn_global_load_lds((gu32*)gp, (lu32*)&Bl[(jj * 256 + wv * 64) * 8], 16, 0, 0);
      }
      __syncthreads();
      #pragma unroll
      for (int kk = 0; kk < 2; kk++){
        int kx = kk * 64 + g * 16;
        int sw = kx ^ ((r & 7) << 4);
        bf16x8 a0 = *(const bf16x8*)((const char*)Al + (wv * 32 + r) * 128 + sw);
        bf16x8 a1 = *(const bf16x8*)((const char*)Al + (wv * 32 + 16 + r) * 128 + sw);
        #pragma unroll
        for (int t = 0; t < 4; t++){
          bf16x8 bfr = *(const bf16x8*)((const char*)Bl + (t * 16 + r) * 128 + sw);
          acc[0][t] = __builtin_amdgcn_mfma_f32_16x16x32_bf16(a0, bfr, acc[0][t], 0, 0, 0);
          acc[1][t] = __builtin_amdgcn_mfma_f32_16x16x32_bf16(a1, bfr, acc[1][t], 0, 0, 0);
        }
      }
      __syncthreads();
    }
    int row0 = bi * 128 + wv * 32;
    #pragma unroll
    for (int m = 0; m < 2; m++){
      #pragma unroll
      for (int q = 0; q < 4; q++){
        int row = row0 + m * 16 + g * 4 + q;
        if (row < N){
          #pragma unroll
          for (int tp = 0; tp < 2; tp++){
            int u = __builtin_amdgcn_cvt_pk_fp8_f32(
                acc[m][tp * 2][q], acc[m][tp * 2 + 1][q], 0, false);
            long base = (long)row * 256 + bj * 64 + r;
            xw8[base + (tp * 2) * 16] = (unsigned char)(u & 0xFF);
            xw8[base + (tp * 2 + 1) * 16] = (unsigned char)((u >> 8) & 0xFF);
          }
        }
      }
    }
  } else if (blockIdx.x < 948){
    int wv = tid >> 6, lane = tid & 63;
    f32x4 ws4 = ((const f32x4*)w_s)[lane];
    f32x4 wd4 = ((const f32x4*)w_d)[lane];
    int n0 = (blockIdx.x - 316) * 16 + wv * 4;
    for (int rr = 0; rr < 4; rr++){
      int n = n0 + rr;
      if (n >= N) continue;
      s16x4 xv = *(const s16x4*)(xbf + (long)n * 256 + lane * 4);
      float x0 = bf2f((unsigned short)xv[0]), x1 = bf2f((unsigned short)xv[1]);
      float x2 = bf2f((unsigned short)xv[2]), x3 = bf2f((unsigned short)xv[3]);
      float ps = x0*ws4[0] + x1*ws4[1] + x2*ws4[2] + x3*ws4[3];
      float pd = x0*wd4[0] + x1*wd4[1] + x2*wd4[2] + x3*wd4[3];
      #pragma unroll
      for (int off = 32; off > 0; off >>= 1){
        ps += __shfl_xor(ps, off);
        pd += __shfl_xor(pd, off);
      }
      if (lane == 0){ a_s[n] = ps; a_d[n] = pd; }
    }
  } else {
    int t = (blockIdx.x - 948) * 256 + tid;
    if (t < E + N){
      int s = (t < E) ? ei[t] : (t - E);
      int d = (t < E) ? ei[E + t] : (t - E);
      int pos = atomicAdd(curs + d, 1);
      if (pos < CAP) csr_s[d * CAP + pos] = s;
    }
  }
}

// per dst row: e = exp(leaky(a_s[s]+a_d[d])) on the fly; softmax-weighted
// gather of fp8 xw rows (u32 per lane -> 2x v_cvt_pk_f32_fp8); denom in-loop;
// xb = tanh(acc/esum + b_gat) -> bf16 into A2 left half. 8-way ILP.
__global__ __launch_bounds__(256) void k_gather(
    const int* __restrict__ curs, const int* __restrict__ csr_s,
    const float* __restrict__ a_s, const float* __restrict__ a_d,
    const unsigned* __restrict__ xw32, const float* __restrict__ b_gat,
    short* __restrict__ A2, int N){
  int d = blockIdx.x * 4 + (threadIdx.x >> 6);
  if (d >= N) return;
  int lane = threadIdx.x & 63;
  int cnt = curs[d];
  if (cnt > CAP) cnt = CAP;
  int s0 = d * CAP, s1 = s0 + cnt;
  float add = a_d[d];
  float esum = 0.f;
  float a0 = 0.f, a1 = 0.f, a2 = 0.f, a3 = 0.f;
  int k = s0;
  for (; k + 7 < s1; k += 8){
    int ss[8]; float ee[8]; unsigned ww[8];
    #pragma unroll
    for (int u = 0; u < 8; u++) ss[u] = csr_s[k + u];
    #pragma unroll
    for (int u = 0; u < 8; u++)
      ww[u] = xw32[(long)ss[u] * 64 + lane];
    #pragma unroll
    for (int u = 0; u < 8; u++){
      float al = a_s[ss[u]] + add;
      al = (al > 0.f) ? al : 0.2f * al;
      ee[u] = __expf(al);
    }
    #pragma unroll
    for (int u = 0; u < 8; u++){
      f32x2 lo = __builtin_amdgcn_cvt_pk_f32_fp8(ww[u], false);
      f32x2 hi = __builtin_amdgcn_cvt_pk_f32_fp8(ww[u], true);
      esum += ee[u];
      a0 += ee[u] * lo[0];
      a1 += ee[u] * lo[1];
      a2 += ee[u] * hi[0];
      a3 += ee[u] * hi[1];
    }
  }
  for (; k < s1; k++){
    int s = csr_s[k];
    float al = a_s[s] + add;
    al = (al > 0.f) ? al : 0.2f * al;
    float e = __expf(al);
    unsigned w = xw32[(long)s * 64 + lane];
    f32x2 lo = __builtin_amdgcn_cvt_pk_f32_fp8(w, false);
    f32x2 hi = __builtin_amdgcn_cvt_pk_f32_fp8(w, true);
    esum += e;
    a0 += e * lo[0];
    a1 += e * lo[1];
    a2 += e * hi[0];
    a3 += e * hi[1];
  }
  float inv = 1.0f / esum;
  f32x4 bg = ((const f32x4*)b_gat)[lane];
  s16x4 o;
  o[0] = (short)f2bf(tanhf(a0 * inv + bg[0]));
  o[1] = (short)f2bf(tanhf(a1 * inv + bg[1]));
  o[2] = (short)f2bf(tanhf(a2 * inv + bg[2]));
  o[3] = (short)f2bf(tanhf(a3 * inv + bg[3]));
  *(s16x4*)(A2 + (long)d * 512 + lane * 4) = o;
}

// gates = [xb|h] @ Wcat^T with LDS staging + fused LSTM epilogue.
// Grid (79, 8); block col j covers gate-relative cols [j*32, j*32+32) of all
// 4 gates (B tile rows gate-interleaved) so the epilogue is thread-local.
__global__ __launch_bounds__(256) void k_lstm(
    const short* __restrict__ A2, const short* __restrict__ Wcat,
    const float* __restrict__ c0, float* __restrict__ out, int N){
  __shared__ short Al[128 * 64];
  __shared__ short Bl[128 * 64];
  int w = threadIdx.x >> 6, lane = threadIdx.x & 63;
  int bi = blockIdx.x, j = blockIdx.y;
  int r = lane & 15, g = lane >> 4;
  f32x4 acc[2][8] = {};
  for (int kt = 0; kt < 512; kt += 64){
    #pragma unroll
    for (int jj = 0; jj < 4; jj++){
      int chunk = jj * 256 + w * 64 + lane;
      int row = chunk >> 3, cc = chunk & 7;
      int ccs = cc ^ (row & 7);
      const short* gpa = A2 + (long)(bi * 128 + row) * 512 + kt + ccs * 8;
      __builtin_amdgcn_global_load_lds((gu32*)gpa, (lu32*)&Al[(jj * 256 + w * 64) * 8], 16, 0, 0);
      int brow = (row >> 5) * 256 + j * 32 + (row & 31);
      const short* gpb = Wcat + (long)brow * 512 + kt + ccs * 8;
      __builtin_amdgcn_global_load_lds((gu32*)gpb, (lu32*)&Bl[(jj * 256 + w * 64) * 8], 16, 0, 0);
    }
    __syncthreads();
    #pragma unroll
    for (int kk = 0; kk < 2; kk++){
      int kx = kk * 64 + g * 16;
      int sw = kx ^ ((r & 7) << 4);
      bf16x8 a0 = *(const bf16x8*)((const char*)Al + (w * 32 + r) * 128 + sw);
      bf16x8 a1 = *(const bf16x8*)((const char*)Al + (w * 32 + 16 + r) * 128 + sw);
      #pragma unroll
      for (int t = 0; t < 8; t++){
        bf16x8 b = *(const bf16x8*)((const char*)Bl + (t * 16 + r) * 128 + sw);
        acc[0][t] = __builtin_amdgcn_mfma_f32_16x16x32_bf16(a0, b, acc[0][t], 0, 0, 0);
        acc[1][t] = __builtin_amdgcn_mfma_f32_16x16x32_bf16(a1, b, acc[1][t], 0, 0, 0);
      }
    }
    __syncthreads();
  }
  long sec = (long)N * 256;
  int row0 = bi * 128 + w * 32;
  #pragma unroll
  for (int m = 0; m < 2; m++){
    #pragma unroll
    for (int q = 0; q < 4; q++){
      int row = row0 + m * 16 + g * 4 + q;
      if (row >= N) continue;
      #pragma unroll
      for (int dc = 0; dc < 2; dc++){
        int dcol = j * 32 + dc * 16 + r;
        float iv = acc[m][dc][q];
        float fv = acc[m][dc + 2][q];
        float gv = acc[m][dc + 4][q];
        float ov = acc[m][dc + 6][q];
        long idx = (long)row * 256 + dcol;
        float c0v = c0[idx];
        float ii = 1.f / (1.f + expf(-iv));
        float ff = 1.f / (1.f + expf(-fv));
        float gg = tanhf(gv);
        float oo = 1.f / (1.f + expf(-ov));
        float c1 = ff * c0v + ii * gg;
        float h1 = oo * tanhf(c1);
        out[idx] = h1;
        out[sec + idx] = h1;
        out[2 * sec + idx] = c1;
      }
    }
  }
}

extern "C" void kernel_launch(void* const* d_in, const int* in_sizes, int n_in,
                              void* d_out, int out_size, void* d_ws, size_t ws_size,
                              hipStream_t stream){
  const float* x     = (const float*)d_in[0];
  const int*   ei    = (const int*)d_in[1];
  const float* h     = (const float*)d_in[2];
  const float* c     = (const float*)d_in[3];
  const float* W_gat = (const float*)d_in[4];
  const float* att_s = (const float*)d_in[5];
  const float* att_d = (const float*)d_in[6];
  const float* b_gat = (const float*)d_in[7];
  const float* W_ih  = (const float*)d_in[8];
  const float* W_hh  = (const float*)d_in[9];
  int N  = in_sizes[0] / DIM;   // 10000
  int E  = in_sizes[1] / 2;     // 320000

  char* ws = (char*)d_ws;
  size_t off = 0;
  auto alloc = [&](size_t bytes) -> void* {
    void* p = ws + off;
    off += (bytes + 255) & ~(size_t)255;
    return p;
  };
  unsigned char* xw8 = (unsigned char*)alloc((size_t)MPAD * 256);
  short* A2    = (short*)alloc((size_t)MPAD * 512 * 2);
  short* x_bf  = (short*)alloc((size_t)MPAD * 256 * 2);
  short* Wcat  = (short*)alloc((size_t)1024 * 512 * 2);
  short* WgT   = (short*)alloc((size_t)256 * 256 * 2);
  float* w_s   = (float*)alloc((size_t)256 * 4);
  float* w_d   = (float*)alloc((size_t)256 * 4);
  float* a_s   = (float*)alloc((size_t)N * 4);
  float* a_d   = (float*)alloc((size_t)N * 4);
  int*   curs  = (int*)alloc((size_t)N * 4);
  int*   csr_s = (int*)alloc((size_t)N * CAP * 4);

  float* out = (float*)d_out;

  int nchunks = (E + N + 255) / 256;  // 1290
  hipLaunchKernelGGL(k_front, dim3(1570), dim3(256), 0, stream,
                     x, h, W_gat, att_s, att_d, W_ih, W_hh,
                     x_bf, A2, WgT, Wcat, w_s, w_d, curs, N);
  hipLaunchKernelGGL(k_gx, dim3(948 + nchunks), dim3(256), 0, stream,
                     x_bf, WgT, ei, w_s, w_d, xw8, a_s, a_d,
                     curs, csr_s, E, N);
  hipLaunchKernelGGL(k_gather, dim3(N / 4), dim3(256), 0, stream,
                     curs, csr_s, a_s, a_d, (const unsigned*)xw8, b_gat, A2, N);
  hipLaunchKernelGGL(k_lstm, dim3(MPAD / 128, 8), dim3(256), 0, stream,
                     A2, Wcat, c, out, N);
}